// Round 10
// baseline (54.018 us; speedup 1.0000x reference)
//
#include <hip/hip_runtime.h>
#include <hip/hip_bf16.h>
#include <stdint.h>

// x [8,2048,768] f32, prototypes [1024,768] f32
// out = distances [16384,1024] f32 ++ prototypes copy [1024,768] f32
#define M_ROWS 16384
#define N_COLS 1024
#define K_DIM  768
#define NKT    12   // K_DIM / 64

typedef __attribute__((ext_vector_type(8))) short bf16x8;
typedef __attribute__((ext_vector_type(4))) float f32x4;

__device__ __forceinline__ void async_copy16(void* lds, const void* g) {
  __builtin_amdgcn_global_load_lds(
      (const __attribute__((address_space(1))) unsigned int*)g,
      (__attribute__((address_space(3))) unsigned int*)lds,
      16, 0, 0);
}

__device__ __forceinline__ short b16(float f) {
  __hip_bfloat16 h = __float2bfloat16(f);
  return *reinterpret_cast<short*>(&h);
}

__device__ __forceinline__ unsigned short f2bf(float f) {
  __hip_bfloat16 h = __float2bfloat16(f);
  return *reinterpret_cast<unsigned short*>(&h);
}

// Prototype-only prep: f32->bf16, ||p||^2, f32 passthrough copy (~9 MB).
__global__ void prep_rows(const float* __restrict__ src,
                          unsigned short* __restrict__ dstb,
                          float* __restrict__ sq,
                          float* __restrict__ copy_out) {
  const int wid = threadIdx.x >> 6;
  const int lane = threadIdx.x & 63;
  const int row = blockIdx.x * 4 + wid;
  const float4* r = (const float4*)(src + (size_t)row * K_DIM);
  ushort4* rb = (ushort4*)(dstb + (size_t)row * K_DIM);
  float4* cp = (float4*)(copy_out + (size_t)row * K_DIM);
  float acc = 0.f;
#pragma unroll
  for (int i = 0; i < 3; ++i) {
    float4 v = r[i * 64 + lane];
    acc += v.x * v.x + v.y * v.y + v.z * v.z + v.w * v.w;
    ushort4 u;
    u.x = f2bf(v.x); u.y = f2bf(v.y); u.z = f2bf(v.z); u.w = f2bf(v.w);
    rb[i * 64 + lane] = u;
    cp[i * 64 + lane] = v;
  }
#pragma unroll
  for (int off = 32; off; off >>= 1) acc += __shfl_down(acc, off);
  if (lane == 0) sq[row] = acc;
}

// LDS tile: [128 rows][64 bf16] = 128 B rows, 8 x 16B slots (R5-proven,
// 0 bank conflicts). Stored slot = logical slot ^ (row & 7).
__device__ __forceinline__ bf16x8 ldsfrag(const char* tile, int row, int slot) {
  return *(const bf16x8*)(tile + row * 128 + (((slot ^ (row & 7)) << 4)));
}

// 128x128 tile, BK=64, 256 thr = 4 waves (2x2), 64x64 out/wave.
// R5's exact LDS-read/MFMA core. Fused A path: global f32 -> regs, ISSUED AT
// LOOP TOP (ALOAD before BSTAGE so the av-wait is vmcnt(4), leaving B's
// global_load_lds in flight; sched_barrier(0) pins the issue point against
// compiler sinking — R7's failure mode, VGPR_Count=88 proved the loads were
// sunk to their use). cvt + swizzled ds_write AFTER the MFMA cluster.
// ||x||^2 fused from exact f32 staging values. One __syncthreads per K-tile.
// 64 KB LDS -> 2 blocks/CU.
__global__ __launch_bounds__(256, 2) void dist_gemm(
    const float* __restrict__ x,
    const __hip_bfloat16* __restrict__ pb,
    const float* __restrict__ psq,
    float* __restrict__ out) {
  __shared__ char ldsA[2][16384];  // bf16 A tile (converted in-kernel)
  __shared__ char ldsB[2][16384];  // bf16 B tile
  __shared__ float xsq_s[128];

  const int flat = blockIdx.x;       // 1024 = 128 bm x 8 bn
  const int xcd = flat & 7;
  const int local = flat >> 3;
  const int bm = xcd * 16 + (local >> 3);  // 0..127
  const int bn = local & 7;                // 0..7

  const int tid = threadIdx.x;
  const int wave = tid >> 6;
  const int lane = tid & 63;
  const int wm = wave >> 1;
  const int wn = wave & 1;
  const int rl = lane & 15;
  const int kq = lane >> 4;   // 0..3

  f32x4 acc[4][4] = {};
  float4 av[4][2];                      // staged A: 4 slot-tasks x 32B
  float ssq[4] = {0.f, 0.f, 0.f, 0.f};

  const float* Abase = x + (size_t)(bm * 128) * K_DIM;
  const __hip_bfloat16* Bbase = pb + (size_t)(bn * 128) * K_DIM;

  // A slot-task: thread t, chunk c -> row = c*32 + (t>>3), k-slot = t&7
  // (8 f32 = 32B). 8 consecutive threads cover one row's 256B: coalesced.
  const int arow = tid >> 3;  // 0..31
  const int aslot = tid & 7;
  // B staging geometry (R5): source slot pre-swizzled (rule #21).
  int bgofs[4];
#pragma unroll
  for (int c = 0; c < 4; ++c) {
    const int row = c * 32 + arow;
    const int g = aslot ^ (row & 7);
    bgofs[c] = row * K_DIM + g * 8;  // bf16 elements
  }

#define BSTAGE(buf, ktile)                                                   \
  do {                                                                       \
    _Pragma("unroll") for (int c = 0; c < 4; ++c)                            \
        async_copy16(&ldsB[buf][(c * 256 + tid) * 16],                       \
                     Bbase + bgofs[c] + (ktile) * 64);                       \
  } while (0)

#define ALOAD(ktile)                                                         \
  do {                                                                       \
    _Pragma("unroll") for (int c = 0; c < 4; ++c) {                          \
      const float* ap = Abase + (size_t)(c * 32 + arow) * K_DIM +            \
                        (ktile) * 64 + aslot * 8;                            \
      av[c][0] = *(const float4*)ap;                                         \
      av[c][1] = *(const float4*)(ap + 4);                                   \
    }                                                                        \
  } while (0)

  // cvt + swizzled ds_write_b128 + fused ||x||^2 (exact f32 values)
#define AWRITE(buf)                                                          \
  do {                                                                       \
    _Pragma("unroll") for (int c = 0; c < 4; ++c) {                          \
      const int row_ = c * 32 + arow;                                        \
      bf16x8 v_;                                                             \
      v_[0] = b16(av[c][0].x); v_[1] = b16(av[c][0].y);                      \
      v_[2] = b16(av[c][0].z); v_[3] = b16(av[c][0].w);                      \
      v_[4] = b16(av[c][1].x); v_[5] = b16(av[c][1].y);                      \
      v_[6] = b16(av[c][1].z); v_[7] = b16(av[c][1].w);                      \
      *(bf16x8*)(&ldsA[buf][row_ * 128 + ((aslot ^ (row_ & 7)) << 4)]) = v_; \
      ssq[c] += av[c][0].x * av[c][0].x + av[c][0].y * av[c][0].y +          \
                av[c][0].z * av[c][0].z + av[c][0].w * av[c][0].w +          \
                av[c][1].x * av[c][1].x + av[c][1].y * av[c][1].y +          \
                av[c][1].z * av[c][1].z + av[c][1].w * av[c][1].w;           \
    }                                                                        \
  } while (0)

  // prologue: tile 0 (serial)
  ALOAD(0);
  BSTAGE(0, 0);
  AWRITE(0);
  __syncthreads();  // drains B async (vmcnt) + A ds_writes (lgkm) + barrier

  for (int kt = 0; kt < NKT; ++kt) {
    const int cur = kt & 1;
    const bool pf = (kt + 1 < NKT);
    if (pf) {
      ALOAD(kt + 1);            // A f32 -> regs FIRST (av-wait = vmcnt(4))
      BSTAGE(cur ^ 1, kt + 1);  // then B async loads (stay in flight)
    }
    // Pin the issue point: without this the compiler sinks the ALOAD
    // global_loads to AWRITE (post-MFMA) and serializes on HBM latency
    // every tile (R7: VGPR_Count=88, MfmaUtil 11%).
    __builtin_amdgcn_sched_barrier(0);

    const char* At = &ldsA[cur][0];
    const char* Bt = &ldsB[cur][0];
    bf16x8 af[4][2], bfr[4][2];
#pragma unroll
    for (int mi = 0; mi < 4; ++mi)
#pragma unroll
      for (int kk = 0; kk < 2; ++kk)
        af[mi][kk] = ldsfrag(At, wm * 64 + mi * 16 + rl, kk * 4 + kq);
#pragma unroll
    for (int ni = 0; ni < 4; ++ni)
#pragma unroll
      for (int kk = 0; kk < 2; ++kk)
        bfr[ni][kk] = ldsfrag(Bt, wn * 64 + ni * 16 + rl, kk * 4 + kq);

    __builtin_amdgcn_s_setprio(1);
#pragma unroll
    for (int mi = 0; mi < 4; ++mi)
#pragma unroll
      for (int ni = 0; ni < 4; ++ni)
#pragma unroll
        for (int kk = 0; kk < 2; ++kk)
          acc[mi][ni] = __builtin_amdgcn_mfma_f32_16x16x32_bf16(
              af[mi][kk], bfr[ni][kk], acc[mi][ni], 0, 0, 0);
    __builtin_amdgcn_s_setprio(0);

    if (pf) AWRITE(cur ^ 1);  // cvt + ds_write into the non-read buffer

    __syncthreads();  // one drain per K-tile: next buffers complete
  }
#undef BSTAGE
#undef ALOAD
#undef AWRITE

  // xsq: each (row, slot) owned by one thread; reduce the 8 slot-threads.
#pragma unroll
  for (int c = 0; c < 4; ++c) {
    ssq[c] += __shfl_xor(ssq[c], 1);
    ssq[c] += __shfl_xor(ssq[c], 2);
    ssq[c] += __shfl_xor(ssq[c], 4);
  }
  if (aslot == 0) {
#pragma unroll
    for (int c = 0; c < 4; ++c) xsq_s[c * 32 + arow] = ssq[c];
  }
  __syncthreads();

  // epilogue: dist = xsq[row] + psq[col] - 2*acc
  // C/D layout: col = lane&15, row = (lane>>4)*4 + reg
  const int c0 = bn * 128 + wn * 64;
#pragma unroll
  for (int mi = 0; mi < 4; ++mi) {
#pragma unroll
    for (int ni = 0; ni < 4; ++ni) {
      const int col = c0 + ni * 16 + rl;
      const float ps = psq[col];
#pragma unroll
      for (int r = 0; r < 4; ++r) {
        const int rloc = wm * 64 + mi * 16 + kq * 4 + r;
        out[(size_t)(bm * 128 + rloc) * N_COLS + col] =
            xsq_s[rloc] + ps - 2.0f * acc[mi][ni][r];
      }
    }
  }
}

extern "C" void kernel_launch(void* const* d_in, const int* in_sizes, int n_in,
                              void* d_out, int out_size, void* d_ws, size_t ws_size,
                              hipStream_t stream) {
  const float* x = (const float*)d_in[0];
  const float* p = (const float*)d_in[1];
  float* out = (float*)d_out;
  char* ws = (char*)d_ws;

  float* psq = (float*)ws;                               // 4 KB
  unsigned short* pbu = (unsigned short*)(ws + 4096);    // 1.5 MB
  float* proto_out = out + (size_t)M_ROWS * N_COLS;

  prep_rows<<<N_COLS / 4, 256, 0, stream>>>(p, pbu, psq, proto_out);

  dist_gemm<<<1024, 256, 0, stream>>>(x, (const __hip_bfloat16*)pbu,
                                      psq, out);
}

// Round 11
// 47.205 us; speedup vs baseline: 1.1443x; 1.1443x over previous
//
#include <hip/hip_runtime.h>
#include <hip/hip_bf16.h>
#include <stdint.h>

// x [8,2048,768] f32, prototypes [1024,768] f32
// out = distances [16384,1024] f32 ++ prototypes copy [1024,768] f32
#define M_ROWS 16384
#define N_COLS 1024
#define K_DIM  768
#define NKT    12   // K_DIM / 64

typedef __attribute__((ext_vector_type(8))) short bf16x8;
typedef __attribute__((ext_vector_type(4))) float f32x4;

__device__ __forceinline__ void async_copy16(void* lds, const void* g) {
  __builtin_amdgcn_global_load_lds(
      (const __attribute__((address_space(1))) unsigned int*)g,
      (__attribute__((address_space(3))) unsigned int*)lds,
      16, 0, 0);
}

__device__ __forceinline__ unsigned short f2bf(float f) {
  __hip_bfloat16 h = __float2bfloat16(f);
  return *reinterpret_cast<unsigned short*>(&h);
}

// Combined prep, one launch: blocks [0,4096) process x rows (4/block);
// blocks [4096,4352) process prototype rows (4/block) incl. f32 passthrough.
__global__ void prep_all(const float* __restrict__ x,
                         const float* __restrict__ p,
                         unsigned short* __restrict__ xb,
                         unsigned short* __restrict__ pbu,
                         float* __restrict__ xsq,
                         float* __restrict__ psq,
                         float* __restrict__ proto_out) {
  const int b = blockIdx.x;
  const int wid = threadIdx.x >> 6;
  const int lane = threadIdx.x & 63;
  const float* src;
  unsigned short* dst;
  float* sq;
  float* cp;
  int row;
  if (b < M_ROWS / 4) {
    row = b * 4 + wid;
    src = x; dst = xb; sq = xsq; cp = nullptr;
  } else {
    row = (b - M_ROWS / 4) * 4 + wid;
    src = p; dst = pbu; sq = psq; cp = proto_out;
  }
  const float4* r = (const float4*)(src + (size_t)row * K_DIM);
  ushort4* rb = (ushort4*)(dst + (size_t)row * K_DIM);
  float4* cpv = cp ? (float4*)(cp + (size_t)row * K_DIM) : nullptr;
  float acc = 0.f;
#pragma unroll
  for (int i = 0; i < 3; ++i) {
    float4 v = r[i * 64 + lane];
    acc += v.x * v.x + v.y * v.y + v.z * v.z + v.w * v.w;
    ushort4 u;
    u.x = f2bf(v.x); u.y = f2bf(v.y); u.z = f2bf(v.z); u.w = f2bf(v.w);
    rb[i * 64 + lane] = u;
    if (cpv) cpv[i * 64 + lane] = v;
  }
#pragma unroll
  for (int off = 32; off; off >>= 1) acc += __shfl_down(acc, off);
  if (lane == 0) sq[row] = acc;
}

// LDS tile: [128 rows][64 bf16] = 128 B rows, 8 x 16B slots (R5-proven,
// 0 bank conflicts). Stored slot = logical slot ^ (row & 7); source
// pre-swizzled for the linear global_load_lds destination (rule #21).
__device__ __forceinline__ bf16x8 ldsfrag(const char* tile, int row, int slot) {
  return *(const bf16x8*)(tile + row * 128 + (((slot ^ (row & 7)) << 4)));
}

// 128x128 tile, BK=64, 256 thr = 4 waves (2x2), 64x64 out per wave.
// T3 minimum-2-phase: STAGE(next) issued first, ds_read+MFMA cover the
// latency, ONE vmcnt(0)+barrier per K-tile. 64 KB LDS -> 2 blocks/CU
// resident; grid=1024 (4 blocks/CU) pipelines prologue/epilogue across
// blocks. Bijective XCD swizzle: each XCD owns 16 contiguous bm panels.
__global__ __launch_bounds__(256, 2) void dist_gemm(
    const __hip_bfloat16* __restrict__ xb,
    const __hip_bfloat16* __restrict__ pb,
    const float* __restrict__ xsq,
    const float* __restrict__ psq,
    float* __restrict__ out) {
  __shared__ char lds[2][2][16384];  // [buf][A|B][128x64 bf16] = 64 KB

  const int flat = blockIdx.x;       // 1024 blocks = 128 bm x 8 bn
  const int xcd = flat & 7;
  const int local = flat >> 3;       // 0..127
  const int bm = xcd * 16 + (local >> 3);  // 0..127
  const int bn = local & 7;                // 0..7

  const int tid = threadIdx.x;
  const int wave = tid >> 6;
  const int lane = tid & 63;
  const int wm = wave >> 1;   // 0..1
  const int wn = wave & 1;    // 0..1
  const int rl = lane & 15;
  const int kq = lane >> 4;   // 0..3

  f32x4 acc[4][4] = {};
  bf16x8 af[4][2], bfr[4][2];

  const __hip_bfloat16* Abase = xb + (size_t)(bm * 128) * K_DIM;
  const __hip_bfloat16* Bbase = pb + (size_t)(bn * 128) * K_DIM;

  // staging: 16 KB per operand tile = 1024 x 16B chunks; thread t, chunk c:
  // idx = c*256+t -> row = idx>>3, stored slot = t&7; source pre-swizzled.
  int gofs[4];
#pragma unroll
  for (int c = 0; c < 4; ++c) {
    const int row = c * 32 + (tid >> 3);
    const int g = (tid & 7) ^ (row & 7);
    gofs[c] = row * K_DIM + g * 8;  // bf16 elements
  }

#define STAGE(buf, ktile)                                                   \
  do {                                                                      \
    _Pragma("unroll") for (int c = 0; c < 4; ++c) {                         \
      const int lofs = (c * 256 + tid) * 16;                                \
      async_copy16(&lds[buf][0][0] + lofs, Abase + gofs[c] + (ktile) * 64); \
      async_copy16(&lds[buf][1][0] + lofs, Bbase + gofs[c] + (ktile) * 64); \
    }                                                                       \
  } while (0)

  // prologue
  STAGE(0, 0);
  asm volatile("s_waitcnt vmcnt(0)" ::: "memory");
  asm volatile("s_barrier" ::: "memory");

  for (int kt = 0; kt < NKT; ++kt) {
    const int cur = kt & 1;
    if (kt + 1 < NKT) STAGE(cur ^ 1, kt + 1);  // issue next-tile loads FIRST

    const char* At = &lds[cur][0][0];
    const char* Bt = &lds[cur][1][0];
#pragma unroll
    for (int mi = 0; mi < 4; ++mi)
#pragma unroll
      for (int kk = 0; kk < 2; ++kk)
        af[mi][kk] = ldsfrag(At, wm * 64 + mi * 16 + rl, kk * 4 + kq);
#pragma unroll
    for (int ni = 0; ni < 4; ++ni)
#pragma unroll
      for (int kk = 0; kk < 2; ++kk)
        bfr[ni][kk] = ldsfrag(Bt, wn * 64 + ni * 16 + rl, kk * 4 + kq);

    __builtin_amdgcn_s_setprio(1);
#pragma unroll
    for (int mi = 0; mi < 4; ++mi)
#pragma unroll
      for (int ni = 0; ni < 4; ++ni)
#pragma unroll
        for (int kk = 0; kk < 2; ++kk)
          acc[mi][ni] = __builtin_amdgcn_mfma_f32_16x16x32_bf16(
              af[mi][kk], bfr[ni][kk], acc[mi][ni], 0, 0, 0);
    __builtin_amdgcn_s_setprio(0);

    // single per-tile sync: next buffer complete, this buffer's reads already
    // consumed by the MFMAs above (no WAR on the re-stage after the barrier).
    asm volatile("s_waitcnt vmcnt(0)" ::: "memory");
    asm volatile("s_barrier" ::: "memory");
  }
#undef STAGE

  // epilogue: dist = xsq[row] + psq[col] - 2*acc
  // C/D layout: col = lane&15, row = (lane>>4)*4 + reg
  const int c0 = bn * 128 + wn * 64;
  const int r0 = bm * 128 + wm * 64;
#pragma unroll
  for (int mi = 0; mi < 4; ++mi) {
#pragma unroll
    for (int ni = 0; ni < 4; ++ni) {
      const int col = c0 + ni * 16 + rl;
      const float ps = psq[col];
#pragma unroll
      for (int r = 0; r < 4; ++r) {
        const int row = r0 + mi * 16 + kq * 4 + r;
        out[(size_t)row * N_COLS + col] = xsq[row] + ps - 2.0f * acc[mi][ni][r];
      }
    }
  }
}

extern "C" void kernel_launch(void* const* d_in, const int* in_sizes, int n_in,
                              void* d_out, int out_size, void* d_ws, size_t ws_size,
                              hipStream_t stream) {
  const float* x = (const float*)d_in[0];
  const float* p = (const float*)d_in[1];
  float* out = (float*)d_out;
  char* ws = (char*)d_ws;

  float* xsq = (float*)ws;                                   // 64 KB
  float* psq = (float*)(ws + 65536);                         // 4 KB
  unsigned short* xb = (unsigned short*)(ws + 69632);        // 24 MB
  unsigned short* pbu = xb + (size_t)M_ROWS * K_DIM;         // 1.5 MB
  float* proto_out = out + (size_t)M_ROWS * N_COLS;

  prep_all<<<M_ROWS / 4 + N_COLS / 4, 256, 0, stream>>>(x, p, xb, pbu, xsq,
                                                        psq, proto_out);

  dist_gemm<<<1024, 256, 0, stream>>>((const __hip_bfloat16*)xb,
                                      (const __hip_bfloat16*)pbu,
                                      xsq, psq, out);
}